// Round 7
// baseline (490.119 us; speedup 1.0000x reference)
//
#include <hip/hip_runtime.h>
#include <hip/hip_bf16.h>
#include <math.h>

#define BQ   32
#define SEQ  1024
#define DM   768
#define NH   12
#define DH   64
#define CQKV 2304
#define MROWS (BQ * SEQ)   // 32768
#define NT   12            // K tiles (768/64) for both GEMMs

#define QSCALE 0.1803368801f   // log2(e)/8 : folded into Q at the qkv epilogue

typedef __attribute__((ext_vector_type(8))) short  short8;   // 8 bf16 = 4 VGPRs
typedef __attribute__((ext_vector_type(4))) short  short4v;  // 8 B
typedef __attribute__((ext_vector_type(4))) float  floatx4;

using bf16 = __hip_bfloat16;

// global -> LDS async copy, 16 B per lane. LDS dest is wave-uniform base +
// lane*16 (m104); global side is a per-lane gather (pre-swizzle goes here).
#define G2L(g, l) __builtin_amdgcn_global_load_lds(                              \
        (const __attribute__((address_space(1))) void*)(g),                      \
        (__attribute__((address_space(3))) void*)(l), 16, 0, 0)

#define WAVE_SYNC() __builtin_amdgcn_wave_barrier()
#define MFMA16(a, b, c) __builtin_amdgcn_mfma_f32_16x16x32_bf16((a), (b), (c), 0, 0, 0)

// ---------------------------------------------------------------------------
__global__ void cast_f32_bf16(const float* __restrict__ in, bf16* __restrict__ out,
                              int n4)
{
    int idx = blockIdx.x * blockDim.x + threadIdx.x;
    if (idx < n4) {
        float4 v = ((const float4*)in)[idx];
        bf16 o[4] = { __float2bfloat16(v.x), __float2bfloat16(v.y),
                      __float2bfloat16(v.z), __float2bfloat16(v.w) };
        ((ushort4*)out)[idx] = *(const ushort4*)o;
    }
}

// ---------------------------------------------------------------------------
// LDS-tiled transpose+cast: coalesced reads AND writes. 32x32 f32 tile,
// padded leading dim (33) for conflict-free transposed reads.
// Grid: (C/32, R/32), 256 threads.
// ---------------------------------------------------------------------------
__global__ __launch_bounds__(256) void transpose_cast(
    const float* __restrict__ in, bf16* __restrict__ out, int R, int C)
{
    __shared__ float tile[32][33];
    const int lx = threadIdx.x & 31, ly = threadIdx.x >> 5;   // 32 x 8
    const int c0 = blockIdx.x * 32, r0 = blockIdx.y * 32;
    #pragma unroll
    for (int p = 0; p < 4; ++p)
        tile[ly + p * 8][lx] = in[(size_t)(r0 + ly + p * 8) * C + c0 + lx];
    __syncthreads();
    #pragma unroll
    for (int p = 0; p < 4; ++p)
        out[(size_t)(c0 + ly + p * 8) * R + r0 + lx] =
            __float2bfloat16(tile[lx][ly + p * 8]);
}

// ---------------------------------------------------------------------------
// Pipelined 256x256 GEMM mainloop, ROUND-7: 4-phase quadrant schedule.
// 8 waves (512 thr), wave grid 2M x 4N, per-wave 128x64 (acc 8x4). BK=64.
// LDS A[2][256][64] + B[2][256][64] = 128 KB double-buffered.
// Staging/buffering/vmcnt IDENTICAL to round-6 (stage(T+1) burst at tile top,
// counted vmcnt(8), raw barriers; both-sides slot^=(row&7) swizzle). The only
// change: the per-tile compute is split into 4 {ds_read quadrant-subtile ->
// barrier -> setprio(1) 16xMFMA setprio(0) -> barrier} phases. Mechanism
// (T3->T5): waves on a SIMD get role diversity within a phase (one reads LDS
// while the other runs MFMA, setprio arbitrates toward the matrix pipe);
// reads for phase p+1 overlap phase p's MFMAs across waves. Data flow is
// bit-identical to round-6 -- added barriers only over-synchronize.
//   ph0: af[0..4)x2ks + bf[0..2)x2ks (12 reads) | MFMA m0-3 x n0-1
//   ph1: bf[2..4)x2ks (4 reads)                 | MFMA m0-3 x n2-3
//   ph2: af[4..8)x2ks (8 reads)                 | MFMA m4-7 x n0-1
//   ph3: (0 reads)                              | MFMA m4-7 x n2-3
// ---------------------------------------------------------------------------
__device__ __forceinline__ void mainloop256(
    const bf16* __restrict__ X, const bf16* __restrict__ WT,
    int m0, int n0, int w, int lane, int lr, int lq,
    bf16 (*Asm)[256][64], bf16 (*Bsm)[256][64], floatx4 acc[8][4])
{
    const int wm = (w >> 2) * 128, wn = (w & 3) * 64;
    const int lr7 = lr & 7;
    const int sr = lane >> 3;                 // staging row within 8-row chunk
    const int ss = ((lane & 7) ^ sr) * 8;     // inverse-swizzled source slot
    const bf16* gA = X  + (size_t)(m0 + w * 8 + sr) * DM + ss;
    const bf16* gB = WT + (size_t)(n0 + w * 8 + sr) * DM + ss;

    auto stage = [&](int T) {                 // T compile-time (unrolled loop)
        const int bI = T & 1;
        #pragma unroll
        for (int r = 0; r < 4; ++r)           // A: 256 rows = 4 rounds x 8 waves x 8 rows
            G2L(gA + (size_t)(r * 64) * DM + T * 64, &Asm[bI][r * 64 + w * 8][0]);
        #pragma unroll
        for (int r = 0; r < 4; ++r)           // B: 256 rows = 4 rounds
            G2L(gB + (size_t)(r * 64) * DM + T * 64, &Bsm[bI][r * 64 + w * 8][0]);
    };

    stage(0);                                 // prologue: tile 0 in flight

    #pragma unroll
    for (int T = 0; T < NT; ++T) {
        if (T + 1 < NT) {
            stage(T + 1);                     // 8 younger loads issued
            asm volatile("s_waitcnt vmcnt(8)" ::: "memory");   // T landed
        } else {
            asm volatile("s_waitcnt vmcnt(0)" ::: "memory");   // tail drain
        }
        __builtin_amdgcn_s_barrier();         // publish tile T to all waves
        asm volatile("" ::: "memory");

        const int bI = T & 1;
        short8 af[8][2], bfr[4][2];

        // ---------------- phase 0 ----------------
        #pragma unroll
        for (int ks = 0; ks < 2; ++ks) {
            #pragma unroll
            for (int m = 0; m < 4; ++m)
                af[m][ks] = *(const short8*)(
                    &Asm[bI][wm + m * 16 + lr][((ks * 4 + lq) ^ lr7) * 8]);
            #pragma unroll
            for (int n = 0; n < 2; ++n)
                bfr[n][ks] = *(const short8*)(
                    &Bsm[bI][wn + n * 16 + lr][((ks * 4 + lq) ^ lr7) * 8]);
        }
        asm volatile("" ::: "memory");
        __builtin_amdgcn_s_barrier();
        __builtin_amdgcn_s_setprio(1);
        #pragma unroll
        for (int ks = 0; ks < 2; ++ks)
            #pragma unroll
            for (int m = 0; m < 4; ++m)
                #pragma unroll
                for (int n = 0; n < 2; ++n)
                    acc[m][n] = MFMA16(af[m][ks], bfr[n][ks], acc[m][n]);
        __builtin_amdgcn_s_setprio(0);
        asm volatile("" ::: "memory");
        __builtin_amdgcn_s_barrier();

        // ---------------- phase 1 ----------------
        #pragma unroll
        for (int ks = 0; ks < 2; ++ks)
            #pragma unroll
            for (int n = 2; n < 4; ++n)
                bfr[n][ks] = *(const short8*)(
                    &Bsm[bI][wn + n * 16 + lr][((ks * 4 + lq) ^ lr7) * 8]);
        asm volatile("" ::: "memory");
        __builtin_amdgcn_s_barrier();
        __builtin_amdgcn_s_setprio(1);
        #pragma unroll
        for (int ks = 0; ks < 2; ++ks)
            #pragma unroll
            for (int m = 0; m < 4; ++m)
                #pragma unroll
                for (int n = 2; n < 4; ++n)
                    acc[m][n] = MFMA16(af[m][ks], bfr[n][ks], acc[m][n]);
        __builtin_amdgcn_s_setprio(0);
        asm volatile("" ::: "memory");
        __builtin_amdgcn_s_barrier();

        // ---------------- phase 2 ----------------
        #pragma unroll
        for (int ks = 0; ks < 2; ++ks)
            #pragma unroll
            for (int m = 4; m < 8; ++m)
                af[m][ks] = *(const short8*)(
                    &Asm[bI][wm + m * 16 + lr][((ks * 4 + lq) ^ lr7) * 8]);
        asm volatile("" ::: "memory");
        __builtin_amdgcn_s_barrier();
        __builtin_amdgcn_s_setprio(1);
        #pragma unroll
        for (int ks = 0; ks < 2; ++ks)
            #pragma unroll
            for (int m = 4; m < 8; ++m)
                #pragma unroll
                for (int n = 0; n < 2; ++n)
                    acc[m][n] = MFMA16(af[m][ks], bfr[n][ks], acc[m][n]);
        __builtin_amdgcn_s_setprio(0);
        asm volatile("" ::: "memory");
        __builtin_amdgcn_s_barrier();

        // ---------------- phase 3 ----------------
        __builtin_amdgcn_s_setprio(1);
        #pragma unroll
        for (int ks = 0; ks < 2; ++ks)
            #pragma unroll
            for (int m = 4; m < 8; ++m)
                #pragma unroll
                for (int n = 2; n < 4; ++n)
                    acc[m][n] = MFMA16(af[m][ks], bfr[n][ks], acc[m][n]);
        __builtin_amdgcn_s_setprio(0);
        asm volatile("" ::: "memory");
        __builtin_amdgcn_s_barrier();         // reads of buf[T&1] done
        asm volatile("" ::: "memory");
    }
}

// ---------------------------------------------------------------------------
// QKV projection -> Q[b,h,n,d] (pre-scaled by log2(e)/8), K[b,h,n,d], Vt[b,h,d,n]
// Grid: 1-D 1152 (128 m x 9 n at 256x256), XCD-chunked. Dynamic LDS 131072 B.
// ---------------------------------------------------------------------------
__global__ __launch_bounds__(512, 2) void gemm_qkv(
    const bf16* __restrict__ X, const bf16* __restrict__ WT,
    const float* __restrict__ bias,
    bf16* __restrict__ Qo, bf16* __restrict__ Ko, bf16* __restrict__ Vt)
{
    extern __shared__ __align__(16) char smem[];
    auto Asm = (bf16(*)[256][64])smem;                       // 2 x 32 KB
    auto Bsm = (bf16(*)[256][64])(smem + 2 * 256 * 64 * 2);  // 2 x 32 KB
    auto Es  = (bf16(*)[64][72])smem;                        // alias, post-loop

    const int t = threadIdx.x, w = t >> 6, lane = t & 63;
    const int lr = lane & 15, lq = lane >> 4;
    const int id = blockIdx.x;
    const int xcd = id & 7, o = id >> 3;        // o in [0,144)
    const int m0 = (xcd * 16 + o / 9) * 256;
    const int n0 = (o % 9) * 256;

    floatx4 acc[8][4] = {};
    mainloop256(X, WT, m0, n0, w, lane, lr, lq, Asm, Bsm, acc);

    const int wm = (w >> 2) * 128, wn = (w & 3) * 64;
    const int cb = n0 + wn;                     // wave's first qkv-col (64-aligned)
    const int which = cb / DM;                  // 0=Q 1=K 2=V (uniform per wave)
    const int hb    = (cb % DM) / DH;
    const int nbw   = m0 + wm;                  // wave's first token row (128-aligned)
    const int bb    = nbw >> 10, nloc = nbw & (SEQ - 1);
    const size_t head = (size_t)bb * NH + hb;
    const float qmul = (which == 0) ? QSCALE : 1.0f;

    if (which != 2) {
        // ---- Q/K: rows = n (4 chunks of 32), cols = d (64)
        bf16* Out = (which ? Ko : Qo) + (head * SEQ + nloc) * DH;
        #pragma unroll
        for (int c2 = 0; c2 < 4; ++c2) {
            #pragma unroll
            for (int ah = 0; ah < 2; ++ah) {
                const int m = c2 * 2 + ah;
                #pragma unroll
                for (int n = 0; n < 4; ++n) {
                    const float bv = bias[cb + n * 16 + lr];
                    #pragma unroll
                    for (int rr = 0; rr < 4; ++rr)
                        Es[w][ah * 16 + lq * 4 + rr][n * 16 + lr] =
                            __float2bfloat16((acc[m][n][rr] + bv) * qmul);
                }
            }
            WAVE_SYNC();   // per-wave region; wave LDS ops are in-order
            #pragma unroll
            for (int i = 0; i < 4; ++i) {
                const int r = i * 8 + (lane >> 3), s = lane & 7;
                short8 vv = *(const short8*)(&Es[w][r][s * 8]);
                *(short8*)(Out + (size_t)(c2 * 32 + r) * DH + s * 8) = vv;
            }
            WAVE_SYNC();   // next chunk's writes follow this chunk's reads
        }
    } else {
        // ---- V: rows = d (64), cols = token (4 chunks of 32) -> Vt[b,h,d,n]
        bf16* Out = Vt + head * (size_t)(DH * SEQ) + nloc;
        #pragma unroll
        for (int mc = 0; mc < 4; ++mc) {
            #pragma unroll
            for (int ah = 0; ah < 2; ++ah) {
                const int m = mc * 2 + ah;
                #pragma unroll
                for (int n = 0; n < 4; ++n) {
                    const float bv = bias[cb + n * 16 + lr];
                    #pragma unroll
                    for (int rr = 0; rr < 4; ++rr)
                        Es[w][n * 16 + lr][ah * 16 + lq * 4 + rr] =
                            __float2bfloat16(acc[m][n][rr] + bv);
                }
            }
            WAVE_SYNC();
            #pragma unroll
            for (int i = 0; i < 4; ++i) {
                const int r = i * 16 + (lane >> 2), s = lane & 3;
                short8 vv = *(const short8*)(&Es[w][r][s * 8]);
                *(short8*)(Out + (size_t)r * SEQ + mc * 32 + s * 8) = vv;
            }
            WAVE_SYNC();
        }
    }
}

// ---------------------------------------------------------------------------
// Output projection: O(32768x768 bf16) @ Wproj + b -> out (fp32 row-major)
// Grid: 1-D 384 (128 m x 3 n at 256x256), XCD-chunked. Dynamic LDS 131072 B.
// ---------------------------------------------------------------------------
__global__ __launch_bounds__(512, 2) void gemm_proj(
    const bf16* __restrict__ A, const bf16* __restrict__ WT,
    const float* __restrict__ bias, float* __restrict__ out)
{
    extern __shared__ __align__(16) char smem[];
    auto Asm = (bf16(*)[256][64])smem;
    auto Bsm = (bf16(*)[256][64])(smem + 2 * 256 * 64 * 2);

    const int t = threadIdx.x, w = t >> 6, lane = t & 63;
    const int lr = lane & 15, lq = lane >> 4;
    const int id = blockIdx.x;
    const int xcd = id & 7, o = id >> 3;        // o in [0,48)
    const int m0 = (xcd * 16 + o / 3) * 256;
    const int n0 = (o % 3) * 256;

    floatx4 acc[8][4] = {};
    mainloop256(A, WT, m0, n0, w, lane, lr, lq, Asm, Bsm, acc);

    const int wm = (w >> 2) * 128, wn = (w & 3) * 64;
    #pragma unroll
    for (int n = 0; n < 4; ++n) {
        const float bv = bias[n0 + wn + n * 16 + lr];
        #pragma unroll
        for (int m = 0; m < 8; ++m) {
            const int rg = m0 + wm + m * 16 + lq * 4;
            #pragma unroll
            for (int rr = 0; rr < 4; ++rr)
                out[(size_t)(rg + rr) * DM + n0 + wn + n * 16 + lr] =
                    acc[m][n][rr] + bv;
        }
    }
}

// ---------------------------------------------------------------------------
// Flash attention. Grid: 3072 blocks (1-D, XCD-remapped), 256 thr = 4 waves.
// (unchanged this round -- see round-6 notes: 40 KB LDS -> 4 blocks/CU,
//  2-half KV processing, ones-MFMA row sums, shuffle-free epilogue)
// ---------------------------------------------------------------------------
__global__ __launch_bounds__(256) void flash_attn(
    const bf16* __restrict__ Q, const bf16* __restrict__ K,
    const bf16* __restrict__ Vt, bf16* __restrict__ O)
{
    __shared__ __align__(16) bf16 Ks[2][2][64][32];    // 16 KB
    __shared__ __align__(16) bf16 Vs[2][2][64][32];    // 16 KB
    __shared__ __align__(16) bf16 Plds[4][32][32];     // 8 KB, per-wave 32q x 32kv half
    const int w = threadIdx.x >> 6, lane = threadIdx.x & 63;
    const int lr = lane & 15, lq = lane >> 4;

    const int fid = blockIdx.x;                       // 0..3071
    const int g   = (fid & 7) + ((fid >> 6) << 3);    // (b,h) group, 0..383
    const int x   = (fid >> 3) & 7;                   // q-block within group
    const int h   = g % NH, b = g / NH;
    const int qb  = x * 128 + w * 32;                 // wave's first q-row

    const bf16* Qh = Q  + (size_t)(b * NH + h) * SEQ * DH;
    const bf16* Kh = K  + (size_t)(b * NH + h) * SEQ * DH;
    const bf16* Vh = Vt + (size_t)(b * NH + h) * DH * SEQ;

    short8 bq[2][2];
    #pragma unroll
    for (int qs = 0; qs < 2; ++qs) {
        bq[qs][0] = *(const short8*)(Qh + (size_t)(qb + qs * 16 + lr) * DH + lq * 8);
        bq[qs][1] = *(const short8*)(Qh + (size_t)(qb + qs * 16 + lr) * DH + 32 + lq * 8);
    }

    floatx4 acc[2][4] = {};
    floatx4 accl[2] = {};                              // row-sums via ones-MFMA
    short8 vones;
    #pragma unroll
    for (int i = 0; i < 8; ++i) vones[i] = (short)0x3F80;   // bf16 1.0

    const int srow = lane >> 2;
    const int ssw  = ((lane & 3) ^ ((lane >> 3) & 3)) * 8;   // K/V staging swizzle
    const int rsw  = (lr >> 1) & 3;                          // K/V read-side XOR
    const int psw  = (lr >> 1) & 3;                          // P slot swizzle key

    const bf16* gsrc[4];
    bf16*       ldst[4];
    #pragma unroll
    for (int i = 0; i < 4; ++i) {
        const int idx = w * 4 + i;
        if (idx < 8) {   // K: half hh, row-group gg
            const int hh = idx >> 2, gg = idx & 3;
            gsrc[i] = Kh + (size_t)(gg * 16 + srow) * DH + hh * 32 + ssw;
            ldst[i] = &Ks[0][hh][gg * 16][0];
        } else {         // V: half hh (kv), row-group gg (d)
            const int vv = idx - 8, hh = vv >> 2, gg = vv & 3;
            gsrc[i] = Vh + (size_t)(gg * 16 + srow) * SEQ + hh * 32 + ssw;
            ldst[i] = &Vs[0][hh][gg * 16][0];
        }
    }
    const int gstep = (w < 2) ? 64 * DH : 64;

    auto stage = [&](int bi) {
        #pragma unroll
        for (int i = 0; i < 4; ++i) {
            G2L(gsrc[i], ldst[i] + bi * 4096);
            gsrc[i] += gstep;
        }
    };

    stage(0);
    __syncthreads();

    int cur = 0;
    for (int j0 = 0; j0 < SEQ; j0 += 64) {
        if (j0 + 64 < SEQ) stage(cur ^ 1);

        short8 ak[4][2];
        #pragma unroll
        for (int jt = 0; jt < 4; ++jt) {
            ak[jt][0] = *(const short8*)(&Ks[cur][0][jt * 16 + lr][(lq ^ rsw) * 8]);
            ak[jt][1] = *(const short8*)(&Ks[cur][1][jt * 16 + lr][(lq ^ rsw) * 8]);
        }

        #pragma unroll
        for (int hh = 0; hh < 2; ++hh) {       // kv-half hh: kv j0+32hh .. +31
            // ---- QK^T for this half, exp, P -> LDS (32 cols, slot-swizzled)
            #pragma unroll
            for (int qs = 0; qs < 2; ++qs) {
                #pragma unroll
                for (int j2 = 0; j2 < 2; ++j2) {
                    const int jt = hh * 2 + j2;
                    floatx4 c = {};
                    c = MFMA16(ak[jt][0], bq[qs][0], c);
                    c = MFMA16(ak[jt][1], bq[qs][1], c);
                    bf16 pk[4];
                    #pragma unroll
                    for (int r = 0; r < 4; ++r)
                        pk[r] = __float2bfloat16(__builtin_amdgcn_exp2f(c[r]));
                    const int slot = (2 * j2 + (lq >> 1)) ^ psw;
                    *(short4v*)(&Plds[w][qs * 16 + lr][slot * 8 + (lq & 1) * 4]) =
                        *(const short4v*)pk;
                }
            }
            WAVE_SYNC();   // per-wave LDS region; wave LDS ops are in-order

            // ---- PV for this half: A = P rows, B = Vs[hh] rows; + ones-MFMA
            short8 ap[2], bvh[4];
            #pragma unroll
            for (int qs = 0; qs < 2; ++qs)
                ap[qs] = *(const short8*)(&Plds[w][qs * 16 + lr][(lq ^ psw) * 8]);
            #pragma unroll
            for (int dt = 0; dt < 4; ++dt)
                bvh[dt] = *(const short8*)(&Vs[cur][hh][dt * 16 + lr][(lq ^ rsw) * 8]);
            __builtin_amdgcn_s_setprio(1);
            #pragma unroll
            for (int qs = 0; qs < 2; ++qs) {
                accl[qs] = MFMA16(ap[qs], vones, accl[qs]);
                #pragma unroll
                for (int dt = 0; dt < 4; ++dt)
                    acc[qs][dt] = MFMA16(ap[qs], bvh[dt], acc[qs][dt]);
            }
            __builtin_amdgcn_s_setprio(0);
            WAVE_SYNC();   // ap reads done before next half overwrites Plds
        }

        __syncthreads();   // K/V buf reads done + staged tile drained
        cur ^= 1;
    }

    // ---- epilogue: accl rows already match acc rows -- no shuffles needed
    #pragma unroll
    for (int qs = 0; qs < 2; ++qs) {
        float inv[4];
        #pragma unroll
        for (int r = 0; r < 4; ++r)
            inv[r] = 1.f / accl[qs][r];        // l of q-row qs*16+lq*4+r
        #pragma unroll
        for (int dt = 0; dt < 4; ++dt)
            #pragma unroll
            for (int r = 0; r < 4; ++r) {
                const int qi = qb + qs * 16 + lq * 4 + r;
                O[((size_t)b * SEQ + qi) * DM + h * DH + dt * 16 + lr] =
                    __float2bfloat16(acc[qs][dt][r] * inv[r]);
            }
    }
}

// ---------------------------------------------------------------------------
extern "C" void kernel_launch(void* const* d_in, const int* in_sizes, int n_in,
                              void* d_out, int out_size, void* d_ws, size_t ws_size,
                              hipStream_t stream)
{
    const float* x      = (const float*)d_in[0];
    const float* w_qkv  = (const float*)d_in[1];
    const float* b_qkv  = (const float*)d_in[2];
    const float* w_proj = (const float*)d_in[3];
    const float* b_proj = (const float*)d_in[4];
    float* out = (float*)d_out;

    // workspace layout (bf16 elems): wqkvT | wprojT | Xb | Q | K | Vt | O
    bf16* ws = (bf16*)d_ws;
    size_t off = 0;
    bf16* wqkvT  = ws + off; off += (size_t)CQKV * DM;
    bf16* wprojT = ws + off; off += (size_t)DM * DM;
    bf16* Xb  = ws + off; off += (size_t)MROWS * DM;
    bf16* Qb  = ws + off; off += (size_t)BQ * NH * SEQ * DH;
    bf16* Kb  = ws + off; off += (size_t)BQ * NH * SEQ * DH;
    bf16* Vtb = ws + off; off += (size_t)BQ * NH * DH * SEQ;
    bf16* Ob  = ws + off; off += (size_t)MROWS * DM;

    static bool attr_done = false;
    if (!attr_done) {
        (void)hipFuncSetAttribute((const void*)gemm_qkv,
                hipFuncAttributeMaxDynamicSharedMemorySize, 131072);
        (void)hipFuncSetAttribute((const void*)gemm_proj,
                hipFuncAttributeMaxDynamicSharedMemorySize, 131072);
        attr_done = true;
    }

    cast_f32_bf16<<<(MROWS * DM / 4 + 255) / 256, 256, 0, stream>>>(x, Xb, MROWS * DM / 4);
    transpose_cast<<<dim3(CQKV / 32, DM / 32), 256, 0, stream>>>(w_qkv, wqkvT, DM, CQKV);
    transpose_cast<<<dim3(DM / 32, DM / 32), 256, 0, stream>>>(w_proj, wprojT, DM, DM);
    gemm_qkv<<<dim3(1152), 512, 131072, stream>>>(Xb, wqkvT, b_qkv, Qb, Kb, Vtb);
    flash_attn<<<dim3(BQ * NH * (SEQ / 128)), 256, 0, stream>>>(Qb, Kb, Vtb, Ob);
    gemm_proj<<<dim3(384), 512, 131072, stream>>>(Ob, wprojT, b_proj, out);
}